// Round 8
// baseline (136.562 us; speedup 1.0000x reference)
//
#include <hip/hip_runtime.h>
#include <hip/hip_bf16.h>
#include <math.h>

#define BB 2
#define CC 128
#define HH 96
#define WW 96
#define HWX (HH*WW)        // 9216
#define KTOT (CC*9)        // 1152
#define OC 128
#define KHALF 576          // deform K split: 64 channels per half
#define ROWH 600           // 576 + 24 pad; 1200 B row stride (16B-aligned, 12 mod 32 banks)
#define QC 32              // offsets: channels per block
#define PXB 32             // pixels per deform block (2 MFMA px-tiles per wave)
#define NWG (BB*HWX/PXB)   // 576 deform blocks

typedef __attribute__((ext_vector_type(8))) __bf16 bf16x8;
typedef __attribute__((ext_vector_type(4))) __bf16 bf16x4;
typedef __attribute__((ext_vector_type(4))) float floatx4;

// ---------------- K0: fused prep (wrep | wbf | xT), branch per block range -----------
// blocks [0,108): wrep; [108,684): wbf; [684,876): x NCHW->NHWC transpose.
__global__ __launch_bounds__(256) void prep_kernel(const float* __restrict__ pw,
                                                   const float* __restrict__ aw,
                                                   const float* __restrict__ cw,
                                                   const float* __restrict__ x,
                                                   float* __restrict__ wrep,
                                                   __bf16* __restrict__ wbf,
                                                   float* __restrict__ xT)
{
    __shared__ float tile[96 * 129];   // xt branch only; [j][c], +1 pad
    int bid = blockIdx.x;
    int tid = threadIdx.x;

    if (bid < 108) {
        // ---- wrep: pconv_w/adconv_w -> wrep[(c*9+tap)*24 + o] ----
        int t = bid * 256 + tid;    // 0..27647
        if (t < KTOT * 24) {
            int tapch = t / 24;
            int o = t - tapch * 24;
            float v = 0.f;
            if (o < 18)      v = pw[o * KTOT + tapch];
            else if (o < 21) v = aw[(o - 18) * KTOT + tapch];
            wrep[t] = v;
        }
    } else if (bid < 684) {
        // ---- wbf: conv_w fp32 -> bf16, MFMA-fragment-linear layout ----
        // t = ((((wv*2+h)*18 + kt)*2 + f)*64 + lane)*8 + e; contents bit-identical
        // to the [o][k'] layout (k' = h*576 + kt*32 + quad*8 + e).
        int t = (bid - 108) * 256 + tid;
        if (t < KTOT * OC) {
            int e    = t & 7;
            int lane = (t >> 3) & 63;
            int f    = (t >> 9) & 1;
            int rest = t >> 10;          // (wv*2+h)*18 + kt, 0..143
            int kt   = rest % 18;
            int wh   = rest / 18;
            int h    = wh & 1;
            int wv   = wh >> 1;
            int quad = lane >> 4, l15 = lane & 15;
            int o  = wv * 32 + f * 16 + l15;
            int r  = kt * 32 + quad * 8 + e;
            int n  = r >> 6;
            int cl = r & 63;
            int c  = h * 64 + cl;
            wbf[t] = (__bf16)cw[(size_t)o * KTOT + c * 9 + n];
        }
    } else {
        // ---- xt: x NCHW -> NHWC (xT[((b*96+i)*96+j)*128 + c]) ----
        int blk = bid - 684;           // b*96 + i
        int b = blk / HH, i = blk % HH;
        const float* src = x + (size_t)b * CC * HWX + (size_t)i * WW;
        for (int idx = tid; idx < CC * WW; idx += 256) {
            int c = idx / WW, j = idx - c * WW;
            tile[j * 129 + c] = src[(size_t)c * HWX + j];
        }
        __syncthreads();
        float* dst = xT + ((size_t)b * HWX + (size_t)i * WW) * CC;
        for (int idx = tid; idx < CC * WW; idx += 256) {
            int j = idx >> 7, c = idx & 127;
            dst[idx] = tile[j * 129 + c];
        }
    }
}

// ---------------- K1: offsets conv, scalar-pipe weights, partial-sum outputs ----------
// grid = BB*144*4, 512 thr. Weights wave-uniform per (cc,tap) via readfirstlane ->
// s_load path; LDS carries only per-lane x reads. FMA order per output unchanged.
__global__ __launch_bounds__(512) void offsets_kernel(
    const float* __restrict__ x, const float* __restrict__ wrep,
    float* __restrict__ offp, float* __restrict__ adp)
{
    __shared__ float sm[9408];    // [0,3200): xs[32][10][10]; reduce aliases [0,9408)
    int blk = blockIdx.x;
    int cq = blk & 3;
    int rest = blk >> 2;
    int b = rest / 144;
    int t2 = rest % 144;
    int ti = t2 / 12, tj = t2 % 12;
    int i0 = ti * 8, j0 = tj * 8;
    int tid = threadIdx.x;
    float* xs = sm;

    for (int idx = tid; idx < 3200; idx += 512) {
        int cl = idx / 100; int r = idx % 100; int u = r / 10, v = r % 10;
        int gi = i0 + u - 1, gj = j0 + v - 1;
        float val = 0.f;
        if (gi >= 0 && gi < HH && gj >= 0 && gj < WW)
            val = x[((b * CC + cq * QC + cl) * HH + gi) * WW + gj];
        xs[idx] = val;
    }
    __syncthreads();

    int wave = tid >> 6, lane = tid & 63;
    int pi = lane >> 3, pj = lane & 7;
    float acc[21];
#pragma unroll
    for (int o = 0; o < 21; ++o) acc[o] = 0.f;

    const float* wq = wrep + (size_t)(cq * QC) * 216;   // this quarter's weights

    for (int cc = 0; cc < 4; ++cc) {
        int cl = wave * 4 + cc;
        const float* xr = &xs[cl * 100 + pi * 10 + pj];
        int cb = __builtin_amdgcn_readfirstlane(cl * 216);   // SGPR base -> s_load path
        const float* wc = wq + cb;
#pragma unroll
        for (int tap = 0; tap < 9; ++tap) {
            int di = tap / 3, dj = tap % 3;
            float xv = xr[di * 10 + dj];
            const float* wr = wc + tap * 24;   // imm offsets: scalar loads
            acc[0]  += xv * wr[0];  acc[1]  += xv * wr[1];  acc[2]  += xv * wr[2];
            acc[3]  += xv * wr[3];  acc[4]  += xv * wr[4];  acc[5]  += xv * wr[5];
            acc[6]  += xv * wr[6];  acc[7]  += xv * wr[7];  acc[8]  += xv * wr[8];
            acc[9]  += xv * wr[9];  acc[10] += xv * wr[10]; acc[11] += xv * wr[11];
            acc[12] += xv * wr[12]; acc[13] += xv * wr[13]; acc[14] += xv * wr[14];
            acc[15] += xv * wr[15]; acc[16] += xv * wr[16]; acc[17] += xv * wr[17];
            acc[18] += xv * wr[18]; acc[19] += xv * wr[19]; acc[20] += xv * wr[20];
        }
    }
    __syncthreads();                 // xs dead; alias reduce buffer over sm
    if (wave > 0) {
        float* red = &sm[((wave - 1) * 64 + lane) * 21];
#pragma unroll
        for (int o = 0; o < 21; ++o) red[o] = acc[o];
    }
    __syncthreads();
    if (wave == 0) {
#pragma unroll
        for (int r = 0; r < 7; ++r) {
            const float* red = &sm[(r * 64 + lane) * 21];
#pragma unroll
            for (int o = 0; o < 21; ++o) acc[o] += red[o];
        }
        int i = i0 + pi, j = j0 + pj;
        int ij = i * WW + j;
        float* op = offp + (size_t)((b * 4 + cq) * 18) * HWX + ij;
#pragma unroll
        for (int o = 0; o < 18; ++o) op[(size_t)o * HWX] = acc[o];
        float* ap = adp + (size_t)((b * 4 + cq) * 3) * HWX + ij;
#pragma unroll
        for (int o = 0; o < 3; ++o) ap[(size_t)o * HWX] = acc[18 + o];
    }
}

// ---------------- K2: sampling + MFMA GEMM, 32-px tiles (fat tile = half B traffic) ---
// grid = 576 blocks, 256 thr, XCD-swizzled. Each wave: 32 output channels x TWO 16-px
// MFMA tiles (4 accs) -> per-block B stream (295 KB from L2) now covers 2x the output,
// halving total B traffic vs PXB=16. 2-phase h-loop keeps LDS at 47.6 KB (3 blocks/CU).
// Gather: thread = (px=tid>>3, 8ch-group=tid&7); one 64B line per quad; 72 independent
// float4 loads per phase. Per-channel interp expression and 36-step k-accumulation
// order are bit-identical to the verified PXB=16 kernel.
__global__ __launch_bounds__(256, 3) void deform_kernel(
    const float* __restrict__ xT, const float* __restrict__ offp,
    const float* __restrict__ adp, const float* __restrict__ pb,
    const float* __restrict__ ab, const __bf16* __restrict__ wbf,
    float* __restrict__ out)
{
    __shared__ __align__(16) __bf16 xoff[PXB * ROWH];   // 38400 B
    __shared__ int4   qidx[PXB * 9];                    // flat plane offsets (lt,rb,lb,rt)
    __shared__ float4 gwt[PXB * 9];                     // weights, zeroed when OOB

    int tid = threadIdx.x;
    // XCD-aware swizzle: contiguous slab per XCD (NWG % 8 == 0 -> bijective)
    int lb = (blockIdx.x & 7) * (NWG >> 3) + (blockIdx.x >> 3);
    int gid0 = lb * PXB;
    int b  = gid0 / HWX;
    int r0 = gid0 - b * HWX;
    int i  = r0 / WW;
    int j0 = r0 % WW;          // 0, 32, or 64

    for (int t = tid; t < PXB * 9; t += 256) {
        int px = t / 9, n = t % 9;
        int j = j0 + px;
        int ij = i * WW + j;
        float offx = pb[n], offy = pb[9 + n], zad = ab[n % 3];
#pragma unroll
        for (int cq = 0; cq < 4; ++cq) {
            const float* op = offp + (size_t)((b * 4 + cq) * 18) * HWX + ij;
            offx += op[(size_t)n * HWX];
            offy += op[(size_t)(9 + n) * HWX];
            zad  += adp[(size_t)((b * 4 + cq) * 3 + (n % 3)) * HWX + ij];
        }
        float ad   = 2.f * (1.f - 1.f / (1.f + expf(-zad)));
        float pnx = (float)(n / 3 - 1), pny = (float)(n % 3 - 1);
        float pxf = (float)(i + 1) + pnx * (1.f + ad) + offx;
        float pyf = (float)(j + 1) + pny * (1.f + ad) + offy;
        float flx = floorf(pxf), fly = floorf(pyf);
        float qltx = fminf(fmaxf(flx, 0.f), 97.f);
        float qlty = fminf(fmaxf(fly, 0.f), 97.f);
        float qrbx = fminf(fmaxf(flx + 1.f, 0.f), 97.f);
        float qrby = fminf(fmaxf(fly + 1.f, 0.f), 97.f);
        bool mx = (pxf < 1.f) || (pxf > 96.f);
        bool my = (pyf < 1.f) || (pyf > 96.f);
        float pxm = mx ? flx : pxf; pxm = fminf(fmaxf(pxm, 0.f), 97.f);
        float pym = my ? fly : pyf; pym = fminf(fmaxf(pym, 0.f), 97.f);
        float glt = (1.f + (qltx - pxm)) * (1.f + (qlty - pym));
        float grb = (1.f - (qrbx - pxm)) * (1.f - (qrby - pym));
        float glb = (1.f + (qltx - pxm)) * (1.f - (qrby - pym));
        float grt = (1.f - (qrbx - pxm)) * (1.f + (qlty - pym));
        int ilt = (int)qltx, jlt = (int)qlty, irb = (int)qrbx, jrb = (int)qrby;
        bool m_lt = (ilt >= 1) & (ilt <= 96) & (jlt >= 1) & (jlt <= 96);
        bool m_rb = (irb >= 1) & (irb <= 96) & (jrb >= 1) & (jrb <= 96);
        bool m_lb = (ilt >= 1) & (ilt <= 96) & (jrb >= 1) & (jrb <= 96);
        bool m_rt = (irb >= 1) & (irb <= 96) & (jlt >= 1) & (jlt <= 96);
        // folded OOB: weight 0 + safe index 0 == (in-bounds ? x : 0) contribution
        qidx[t] = make_int4(m_lt ? (ilt - 1) * WW + (jlt - 1) : 0,
                            m_rb ? (irb - 1) * WW + (jrb - 1) : 0,
                            m_lb ? (ilt - 1) * WW + (jrb - 1) : 0,
                            m_rt ? (irb - 1) * WW + (jlt - 1) : 0);
        gwt[t]  = make_float4(m_lt ? glt : 0.f, m_rb ? grb : 0.f,
                              m_lb ? glb : 0.f, m_rt ? grt : 0.f);
    }
    __syncthreads();

    int wv = tid >> 6, lane = tid & 63;
    int quad = lane >> 4, l15 = lane & 15;
    int o0 = wv * 32 + l15;
    int o1 = o0 + 16;
    floatx4 acc00 = {0,0,0,0}, acc01 = {0,0,0,0};   // px-tile0 x {o0,o1}
    floatx4 acc10 = {0,0,0,0}, acc11 = {0,0,0,0};   // px-tile1 x {o0,o1}
    const __bf16* arow0 = &xoff[l15 * ROWH];
    const __bf16* arow1 = &xoff[(16 + l15) * ROWH];
    const __bf16* wlan = wbf + (size_t)lane * 8;    // fragment-linear B base

    int gpx = tid >> 3;                 // gather pixel 0..31 (quad-coalesced map)
    int gs  = tid & 7;                  // 8-channel group 0..7
    __bf16* grow = &xoff[gpx * ROWH];
    const int4*   qrow = &qidx[gpx * 9];
    const float4* grw  = &gwt[gpx * 9];
    const float* xb = xT + (size_t)b * HWX * CC + gs * 8;

    for (int h = 0; h < 2; ++h) {
        const float* xh = xb + h * 64;
#pragma unroll
        for (int n = 0; n < 9; ++n) {
            int4 q = qrow[n];
            float4 g = grw[n];
            const float* plt = xh + (size_t)q.x * CC;
            const float* prb = xh + (size_t)q.y * CC;
            const float* plb = xh + (size_t)q.z * CC;
            const float* prt = xh + (size_t)q.w * CC;
            float4 lt0 = *(const float4*)plt, lt1 = *(const float4*)(plt + 4);
            float4 rb0 = *(const float4*)prb, rb1 = *(const float4*)(prb + 4);
            float4 lb0 = *(const float4*)plb, lb1 = *(const float4*)(plb + 4);
            float4 rt0 = *(const float4*)prt, rt1 = *(const float4*)(prt + 4);
            bf16x8 ov;   // same per-channel expression: lt,rb,lb,rt
            ov[0] = (__bf16)(g.x * lt0.x + g.y * rb0.x + g.z * lb0.x + g.w * rt0.x);
            ov[1] = (__bf16)(g.x * lt0.y + g.y * rb0.y + g.z * lb0.y + g.w * rt0.y);
            ov[2] = (__bf16)(g.x * lt0.z + g.y * rb0.z + g.z * lb0.z + g.w * rt0.z);
            ov[3] = (__bf16)(g.x * lt0.w + g.y * rb0.w + g.z * lb0.w + g.w * rt0.w);
            ov[4] = (__bf16)(g.x * lt1.x + g.y * rb1.x + g.z * lb1.x + g.w * rt1.x);
            ov[5] = (__bf16)(g.x * lt1.y + g.y * rb1.y + g.z * lb1.y + g.w * rt1.y);
            ov[6] = (__bf16)(g.x * lt1.z + g.y * rb1.z + g.z * lb1.z + g.w * rt1.z);
            ov[7] = (__bf16)(g.x * lt1.w + g.y * rb1.w + g.z * lb1.w + g.w * rt1.w);
            *(bf16x8*)(grow + n * 64 + gs * 8) = ov;   // k' = tap*64 + cl, 16B store
        }
        __syncthreads();

        const __bf16* wb = wlan + (size_t)((wv * 2 + h) * 18) * 1024;
        for (int kt = 0; kt < 18; ++kt) {
            int kl = kt * 32 + quad * 8;
            bf16x8 a0 = *(const bf16x8*)(arow0 + kl);
            bf16x8 a1 = *(const bf16x8*)(arow1 + kl);
            bf16x8 b0 = *(const bf16x8*)(wb + kt * 1024);
            bf16x8 b1 = *(const bf16x8*)(wb + kt * 1024 + 512);
            acc00 = __builtin_amdgcn_mfma_f32_16x16x32_bf16(a0, b0, acc00, 0, 0, 0);
            acc01 = __builtin_amdgcn_mfma_f32_16x16x32_bf16(a0, b1, acc01, 0, 0, 0);
            acc10 = __builtin_amdgcn_mfma_f32_16x16x32_bf16(a1, b0, acc10, 0, 0, 0);
            acc11 = __builtin_amdgcn_mfma_f32_16x16x32_bf16(a1, b1, acc11, 0, 0, 0);
        }
        __syncthreads();
    }

#pragma unroll
    for (int rr = 0; rr < 4; ++rr) {
        int m0 = quad * 4 + rr;          // pixel within tile, 0..15
        int ja = j0 + m0, jb = j0 + 16 + m0;
        out[((b * OC + o0) * HH + i) * WW + ja] = acc00[rr];
        out[((b * OC + o1) * HH + i) * WW + ja] = acc01[rr];
        out[((b * OC + o0) * HH + i) * WW + jb] = acc10[rr];
        out[((b * OC + o1) * HH + i) * WW + jb] = acc11[rr];
    }
}

extern "C" void kernel_launch(void* const* d_in, const int* in_sizes, int n_in,
                              void* d_out, int out_size, void* d_ws, size_t ws_size,
                              hipStream_t stream)
{
    const float* x  = (const float*)d_in[0];
    const float* cw = (const float*)d_in[1];
    const float* pw = (const float*)d_in[2];
    const float* pb = (const float*)d_in[3];
    const float* aw = (const float*)d_in[4];
    const float* ab = (const float*)d_in[5];
    float* out = (float*)d_out;

    char* ws = (char*)d_ws;
    float*  offp = (float*)ws;                        // 2*4*18*9216 = 663552 fp32
    float*  adp  = offp + BB * 4 * 18 * HWX;          // 2*4*3*9216  = 221184 fp32
    float*  wrep = adp + BB * 4 * 3 * HWX;            // 27648 fp32
    __bf16* wbf  = (__bf16*)(wrep + KTOT * 24);       // 147456 bf16 (16B-aligned)
    float*  xT   = (float*)(wbf + (size_t)KTOT * OC); // 2359296 fp32 (16B-aligned)
    // total ws use: ~13.4 MB

    prep_kernel<<<876, 256, 0, stream>>>(pw, aw, cw, x, wrep, wbf, xT);
    offsets_kernel<<<BB * 144 * 4, 512, 0, stream>>>(x, wrep, offp, adp);
    deform_kernel<<<NWG, 256, 0, stream>>>(xT, offp, adp, pb, ab, wbf, out);
}

// Round 9
// 128.564 us; speedup vs baseline: 1.0622x; 1.0622x over previous
//
#include <hip/hip_runtime.h>
#include <hip/hip_bf16.h>
#include <math.h>

#define BB 2
#define CC 128
#define HH 96
#define WW 96
#define HWX (HH*WW)        // 9216
#define KTOT (CC*9)        // 1152
#define OC 128
#define KHALF 576          // deform K split: 64 channels per half
#define ROWF 1176          // 1152 + 24 pad; 2352 B row stride (16B-aligned, 12 mod 32 banks)
#define QC 32              // offsets: channels per block
#define PXB 16             // pixels per deform block
#define NWG (BB*HWX/PXB)   // 1152 deform blocks

typedef __attribute__((ext_vector_type(8))) __bf16 bf16x8;
typedef __attribute__((ext_vector_type(4))) __bf16 bf16x4;
typedef __attribute__((ext_vector_type(4))) float floatx4;

// ---------------- K0: fused pre (offsets | wbf | xT) — 2-dispatch pipeline ------------
// blocks [0,1152): offsets conv (weights s_loaded DIRECTLY from pw/aw, o-outer loop,
//                  36 contiguous floats per (o,wave) -> merged s_load_dwordx16);
// blocks [1152,1440): conv_w fp32 -> bf16 fragment-linear; [1440,1824): x -> NHWC.
// No wrep buffer, no separate prep kernel: saves one ~8 us dispatch.
__global__ __launch_bounds__(512) void pre_kernel(
    const float* __restrict__ pw, const float* __restrict__ aw,
    const float* __restrict__ cw, const float* __restrict__ x,
    float* __restrict__ offp, float* __restrict__ adp,
    __bf16* __restrict__ wbf, float* __restrict__ xT)
{
    __shared__ float sm[9408];   // offsets: xs[32][10][10] in [0,3200), reduce [0,9408);
                                 // xT branch: tile[48][129] = 6192 floats
    int bid = blockIdx.x;
    int tid = threadIdx.x;

    if (bid < 1152) {
        // ================= offsets conv, c-quarter blocks, partial sums =============
        int cq = bid & 3;
        int rest = bid >> 2;
        int b = rest / 144;
        int t2 = rest % 144;
        int ti = t2 / 12, tj = t2 % 12;
        int i0 = ti * 8, j0 = tj * 8;
        float* xs = sm;

        for (int idx = tid; idx < 3200; idx += 512) {
            int cl = idx / 100; int r = idx % 100; int u = r / 10, v = r % 10;
            int gi = i0 + u - 1, gj = j0 + v - 1;
            float val = 0.f;
            if (gi >= 0 && gi < HH && gj >= 0 && gj < WW)
                val = x[((b * CC + cq * QC + cl) * HH + gi) * WW + gj];
            xs[idx] = val;
        }
        __syncthreads();

        int wave = tid >> 6, lane = tid & 63;
        int pi = lane >> 3, pj = lane & 7;

        // hoist the 36 x-values (4 ch x 9 taps) into VGPRs, fully unrolled
        float xv[36];
#pragma unroll
        for (int cc = 0; cc < 4; ++cc) {
            const float* xr = &xs[(wave * 4 + cc) * 100 + pi * 10 + pj];
#pragma unroll
            for (int tap = 0; tap < 9; ++tap)
                xv[cc * 9 + tap] = xr[(tap / 3) * 10 + (tap % 3)];
        }

        // weights: for (o, wave) the 36 floats pw[o*1152 + (cq*32+wave*4)*9 ..+36]
        // are contiguous -> merged scalar loads. Per-acc[o] sum order = (cc,tap)
        // ascending, identical to the previous wrep-based kernel -> bit-identical.
        int cb = __builtin_amdgcn_readfirstlane((cq * QC + wave * 4) * 9);
        float acc[21];
#pragma unroll
        for (int o = 0; o < 21; ++o) {
            const float* wro = (o < 18 ? pw + (size_t)o * KTOT
                                       : aw + (size_t)(o - 18) * KTOT) + cb;
            float a = 0.f;
#pragma unroll
            for (int q = 0; q < 36; ++q) a += xv[q] * wro[q];
            acc[o] = a;
        }
        __syncthreads();                 // xs dead; alias reduce buffer over sm
        if (wave > 0) {
            float* red = &sm[((wave - 1) * 64 + lane) * 21];
#pragma unroll
            for (int o = 0; o < 21; ++o) red[o] = acc[o];
        }
        __syncthreads();
        if (wave == 0) {
#pragma unroll
            for (int r = 0; r < 7; ++r) {
                const float* red = &sm[(r * 64 + lane) * 21];
#pragma unroll
                for (int o = 0; o < 21; ++o) acc[o] += red[o];
            }
            int i = i0 + pi, j = j0 + pj;
            int ij = i * WW + j;
            float* op = offp + (size_t)((b * 4 + cq) * 18) * HWX + ij;
#pragma unroll
            for (int o = 0; o < 18; ++o) op[(size_t)o * HWX] = acc[o];
            float* ap = adp + (size_t)((b * 4 + cq) * 3) * HWX + ij;
#pragma unroll
            for (int o = 0; o < 3; ++o) ap[(size_t)o * HWX] = acc[18 + o];
        }
    } else if (bid < 1440) {
        // ================= wbf: conv_w fp32 -> bf16, fragment-linear ================
        // t = ((((wv*2+h)*18 + kt)*2 + f)*64 + lane)*8 + e; contents bit-identical
        // to the [o][k'] layout (k' = h*576 + kt*32 + quad*8 + e).
        int t = (bid - 1152) * 512 + tid;   // 288 blocks x 512 = 147456 exactly
        if (t < KTOT * OC) {
            int e    = t & 7;
            int lane = (t >> 3) & 63;
            int f    = (t >> 9) & 1;
            int rest = t >> 10;          // (wv*2+h)*18 + kt, 0..143
            int kt   = rest % 18;
            int wh   = rest / 18;
            int h    = wh & 1;
            int wv   = wh >> 1;
            int quad = lane >> 4, l15 = lane & 15;
            int o  = wv * 32 + f * 16 + l15;
            int r  = kt * 32 + quad * 8 + e;
            int n  = r >> 6;
            int cl = r & 63;
            int c  = h * 64 + cl;
            wbf[t] = (__bf16)cw[(size_t)o * KTOT + c * 9 + n];
        }
    } else {
        // ================= xT: x NCHW -> NHWC, 48-col half-rows =====================
        int blk = bid - 1440;            // 0..383: (b, i, jhalf)
        int b  = blk / (HH * 2);
        int rm = blk % (HH * 2);
        int i  = rm >> 1;
        int j0 = (rm & 1) * 48;
        float* tile = sm;                // [jl 48][c 129-pad]
        const float* src = x + (size_t)b * CC * HWX + (size_t)i * WW + j0;
        for (int idx = tid; idx < CC * 48; idx += 512) {
            int c = idx / 48, jl = idx - c * 48;
            tile[jl * 129 + c] = src[(size_t)c * HWX + jl];
        }
        __syncthreads();
        float* dst = xT + ((size_t)b * HWX + (size_t)i * WW + j0) * CC;
        for (int idx = tid; idx < CC * 48; idx += 512) {
            int jl = idx >> 7, c = idx & 127;
            dst[idx] = tile[jl * 129 + c];
        }
    }
}

// ---------------- K1: sampling + MFMA GEMM (exact round-6 structure) ------------------
// grid = 1152 blocks, 256 thr, XCD-swizzled. Single-pass gather of both K-halves
// (72 independent float4 loads), one barrier, 36-step MFMA chain. Quad-coalesced:
// gather lanes 0..3 = 4 consecutive 16B chunks of one pixel; B = fragment-linear
// wave-uniform base + lane*16B. Accumulation order h0 kt0..17, h1 kt0..17.
__global__ __launch_bounds__(256, 3) void deform_kernel(
    const float* __restrict__ xT, const float* __restrict__ offp,
    const float* __restrict__ adp, const float* __restrict__ pb,
    const float* __restrict__ ab, const __bf16* __restrict__ wbf,
    float* __restrict__ out)
{
    __shared__ __align__(16) __bf16 xoff[PXB * ROWF];   // 37632 B, full K rows
    __shared__ int4   qidx[PXB * 9];                    // flat plane offsets (lt,rb,lb,rt)
    __shared__ float4 gwt[PXB * 9];                     // weights, zeroed when OOB

    int tid = threadIdx.x;
    // XCD-aware swizzle: contiguous slab per XCD (NWG % 8 == 0 -> bijective)
    int lb = (blockIdx.x & 7) * (NWG >> 3) + (blockIdx.x >> 3);
    int gid0 = lb * PXB;
    int b  = gid0 / HWX;
    int r0 = gid0 - b * HWX;
    int i  = r0 / WW;
    int j0 = r0 % WW;

    if (tid < PXB * 9) {
        int t = tid;
        int px = t / 9, n = t % 9;
        int j = j0 + px;
        int ij = i * WW + j;
        float offx = pb[n], offy = pb[9 + n], zad = ab[n % 3];
#pragma unroll
        for (int cq = 0; cq < 4; ++cq) {
            const float* op = offp + (size_t)((b * 4 + cq) * 18) * HWX + ij;
            offx += op[(size_t)n * HWX];
            offy += op[(size_t)(9 + n) * HWX];
            zad  += adp[(size_t)((b * 4 + cq) * 3 + (n % 3)) * HWX + ij];
        }
        float ad   = 2.f * (1.f - 1.f / (1.f + expf(-zad)));
        float pnx = (float)(n / 3 - 1), pny = (float)(n % 3 - 1);
        float pxf = (float)(i + 1) + pnx * (1.f + ad) + offx;
        float pyf = (float)(j + 1) + pny * (1.f + ad) + offy;
        float flx = floorf(pxf), fly = floorf(pyf);
        float qltx = fminf(fmaxf(flx, 0.f), 97.f);
        float qlty = fminf(fmaxf(fly, 0.f), 97.f);
        float qrbx = fminf(fmaxf(flx + 1.f, 0.f), 97.f);
        float qrby = fminf(fmaxf(fly + 1.f, 0.f), 97.f);
        bool mx = (pxf < 1.f) || (pxf > 96.f);
        bool my = (pyf < 1.f) || (pyf > 96.f);
        float pxm = mx ? flx : pxf; pxm = fminf(fmaxf(pxm, 0.f), 97.f);
        float pym = my ? fly : pyf; pym = fminf(fmaxf(pym, 0.f), 97.f);
        float glt = (1.f + (qltx - pxm)) * (1.f + (qlty - pym));
        float grb = (1.f - (qrbx - pxm)) * (1.f - (qrby - pym));
        float glb = (1.f + (qltx - pxm)) * (1.f - (qrby - pym));
        float grt = (1.f - (qrbx - pxm)) * (1.f + (qlty - pym));
        int ilt = (int)qltx, jlt = (int)qlty, irb = (int)qrbx, jrb = (int)qrby;
        bool m_lt = (ilt >= 1) & (ilt <= 96) & (jlt >= 1) & (jlt <= 96);
        bool m_rb = (irb >= 1) & (irb <= 96) & (jrb >= 1) & (jrb <= 96);
        bool m_lb = (ilt >= 1) & (ilt <= 96) & (jrb >= 1) & (jrb <= 96);
        bool m_rt = (irb >= 1) & (irb <= 96) & (jlt >= 1) & (jlt <= 96);
        // folded OOB: weight 0 + safe index 0 == (in-bounds ? x : 0) contribution
        qidx[t] = make_int4(m_lt ? (ilt - 1) * WW + (jlt - 1) : 0,
                            m_rb ? (irb - 1) * WW + (jrb - 1) : 0,
                            m_lb ? (ilt - 1) * WW + (jrb - 1) : 0,
                            m_rt ? (irb - 1) * WW + (jlt - 1) : 0);
        gwt[t]  = make_float4(m_lt ? glt : 0.f, m_rb ? grb : 0.f,
                              m_lb ? glb : 0.f, m_rt ? grt : 0.f);
    }
    __syncthreads();

    int wv = tid >> 6, lane = tid & 63;
    int quad = lane >> 4, l15 = lane & 15;
    int o0 = wv * 32 + l15;
    int o1 = o0 + 16;
    floatx4 acc0 = {0,0,0,0}, acc1 = {0,0,0,0};
    const __bf16* arow = &xoff[l15 * ROWF];
    const __bf16* wlan = wbf + (size_t)lane * 8;   // fragment-linear B base

    // ---- single-pass gather: both halves, 72 independent float4 loads ----
    int gpx = tid >> 4;                 // gather pixel (quad-coalesced map)
    int gs  = tid & 15;                 // 4-channel group
    __bf16* grow = &xoff[gpx * ROWF];
    const int4*   qrow = &qidx[gpx * 9];
    const float4* grw  = &gwt[gpx * 9];
    const float* xb = xT + (size_t)b * HWX * CC + gs * 4;

#pragma unroll
    for (int n = 0; n < 9; ++n) {
        int4 q = qrow[n];
        float4 g = grw[n];
        const float* plt = xb + (size_t)q.x * CC;
        const float* prb = xb + (size_t)q.y * CC;
        const float* plb = xb + (size_t)q.z * CC;
        const float* prt = xb + (size_t)q.w * CC;
        float4 lt0 = *(const float4*)plt,        rb0 = *(const float4*)prb;
        float4 lb0 = *(const float4*)plb,        rt0 = *(const float4*)prt;
        float4 lt1 = *(const float4*)(plt + 64), rb1 = *(const float4*)(prb + 64);
        float4 lb1 = *(const float4*)(plb + 64), rt1 = *(const float4*)(prt + 64);
        bf16x4 o0v, o1v;   // same per-channel expression: lt,rb,lb,rt
        o0v[0] = (__bf16)(g.x * lt0.x + g.y * rb0.x + g.z * lb0.x + g.w * rt0.x);
        o0v[1] = (__bf16)(g.x * lt0.y + g.y * rb0.y + g.z * lb0.y + g.w * rt0.y);
        o0v[2] = (__bf16)(g.x * lt0.z + g.y * rb0.z + g.z * lb0.z + g.w * rt0.z);
        o0v[3] = (__bf16)(g.x * lt0.w + g.y * rb0.w + g.z * lb0.w + g.w * rt0.w);
        o1v[0] = (__bf16)(g.x * lt1.x + g.y * rb1.x + g.z * lb1.x + g.w * rt1.x);
        o1v[1] = (__bf16)(g.x * lt1.y + g.y * rb1.y + g.z * lb1.y + g.w * rt1.y);
        o1v[2] = (__bf16)(g.x * lt1.z + g.y * rb1.z + g.z * lb1.z + g.w * rt1.z);
        o1v[3] = (__bf16)(g.x * lt1.w + g.y * rb1.w + g.z * lb1.w + g.w * rt1.w);
        *(bf16x4*)(grow + n * 64 + gs * 4) = o0v;            // k' = tap*64 + cl (h0)
        *(bf16x4*)(grow + KHALF + n * 64 + gs * 4) = o1v;    // k' = 576 + tap*64 + cl
    }
    __syncthreads();

    // ---- barrier-free 36-step MFMA chain (order identical to 2-phase version) ----
#pragma unroll
    for (int h = 0; h < 2; ++h) {
        const __bf16* wb = wlan + (size_t)((wv * 2 + h) * 18) * 1024;
        const __bf16* ah = arow + h * KHALF;
#pragma unroll
        for (int kt = 0; kt < 18; ++kt) {
            bf16x8 a0 = *(const bf16x8*)(ah + kt * 32 + quad * 8);
            bf16x8 b0 = *(const bf16x8*)(wb + kt * 1024);
            bf16x8 b1 = *(const bf16x8*)(wb + kt * 1024 + 512);
            acc0 = __builtin_amdgcn_mfma_f32_16x16x32_bf16(a0, b0, acc0, 0, 0, 0);
            acc1 = __builtin_amdgcn_mfma_f32_16x16x32_bf16(a0, b1, acc1, 0, 0, 0);
        }
    }

#pragma unroll
    for (int rr = 0; rr < 4; ++rr) {
        int m0 = quad * 4 + rr;          // pixel 0..15
        int ja = j0 + m0;
        out[((b * OC + o0) * HH + i) * WW + ja] = acc0[rr];
        out[((b * OC + o1) * HH + i) * WW + ja] = acc1[rr];
    }
}

extern "C" void kernel_launch(void* const* d_in, const int* in_sizes, int n_in,
                              void* d_out, int out_size, void* d_ws, size_t ws_size,
                              hipStream_t stream)
{
    const float* x  = (const float*)d_in[0];
    const float* cw = (const float*)d_in[1];
    const float* pw = (const float*)d_in[2];
    const float* pb = (const float*)d_in[3];
    const float* aw = (const float*)d_in[4];
    const float* ab = (const float*)d_in[5];
    float* out = (float*)d_out;

    char* ws = (char*)d_ws;
    float*  offp = (float*)ws;                        // 2*4*18*9216 = 663552 fp32
    float*  adp  = offp + BB * 4 * 18 * HWX;          // 2*4*3*9216  = 221184 fp32
    __bf16* wbf  = (__bf16*)(adp + BB * 4 * 3 * HWX); // 147456 bf16 (16B-aligned)
    float*  xT   = (float*)(wbf + (size_t)KTOT * OC); // 2359296 fp32 (16B-aligned)
    // total ws use: ~13.3 MB

    pre_kernel<<<1824, 512, 0, stream>>>(pw, aw, cw, x, offp, adp, wbf, xT);
    deform_kernel<<<NWG, 256, 0, stream>>>(xT, offp, adp, pb, ab, wbf, out);
}

// Round 10
// 122.339 us; speedup vs baseline: 1.1163x; 1.0509x over previous
//
#include <hip/hip_runtime.h>
#include <hip/hip_bf16.h>
#include <math.h>

#define BB 2
#define CC 128
#define HH 96
#define WW 96
#define HWX (HH*WW)        // 9216
#define KTOT (CC*9)        // 1152
#define OC 128
#define KHALF 576          // deform K split: 64 channels per half
#define ROWF 1176          // 1152 + 24 pad; 2352 B row stride (16B-aligned)
#define QC 32              // offsets: channels per block
#define PXB 16             // pixels per deform block
#define NWG (BB*HWX/PXB)   // 1152 deform blocks

typedef __attribute__((ext_vector_type(8))) __bf16 bf16x8;
typedef __attribute__((ext_vector_type(4))) __bf16 bf16x4;
typedef __attribute__((ext_vector_type(4))) float floatx4;

// ---------------- K0: fused pre (offsets | wbf | xT-bf16) -----------------------------
// blocks [0,1152): offsets conv (weights s_loaded directly from pw/aw);
// blocks [1152,1440): conv_w fp32 -> bf16 fragment-linear; [1440,1824): x -> NHWC bf16.
__global__ __launch_bounds__(512) void pre_kernel(
    const float* __restrict__ pw, const float* __restrict__ aw,
    const float* __restrict__ cw, const float* __restrict__ x,
    float* __restrict__ offp, float* __restrict__ adp,
    __bf16* __restrict__ wbf, __bf16* __restrict__ xT)
{
    __shared__ float sm[9408];   // offsets: xs[32][10][10] in [0,3200), reduce [0,9408);
                                 // xT branch: tile[48][129] = 6192 floats
    int bid = blockIdx.x;
    int tid = threadIdx.x;

    if (bid < 1152) {
        // ================= offsets conv, c-quarter blocks, partial sums =============
        int cq = bid & 3;
        int rest = bid >> 2;
        int b = rest / 144;
        int t2 = rest % 144;
        int ti = t2 / 12, tj = t2 % 12;
        int i0 = ti * 8, j0 = tj * 8;
        float* xs = sm;

        for (int idx = tid; idx < 3200; idx += 512) {
            int cl = idx / 100; int r = idx % 100; int u = r / 10, v = r % 10;
            int gi = i0 + u - 1, gj = j0 + v - 1;
            float val = 0.f;
            if (gi >= 0 && gi < HH && gj >= 0 && gj < WW)
                val = x[((b * CC + cq * QC + cl) * HH + gi) * WW + gj];
            xs[idx] = val;
        }
        __syncthreads();

        int wave = tid >> 6, lane = tid & 63;
        int pi = lane >> 3, pj = lane & 7;

        // hoist the 36 x-values (4 ch x 9 taps) into VGPRs, fully unrolled
        float xv[36];
#pragma unroll
        for (int cc = 0; cc < 4; ++cc) {
            const float* xr = &xs[(wave * 4 + cc) * 100 + pi * 10 + pj];
#pragma unroll
            for (int tap = 0; tap < 9; ++tap)
                xv[cc * 9 + tap] = xr[(tap / 3) * 10 + (tap % 3)];
        }

        // weights: 36 contiguous floats per (o,wave) -> merged s_loads. Sum order
        // (cc,tap) ascending, identical to previous rounds -> bit-identical.
        int cb = __builtin_amdgcn_readfirstlane((cq * QC + wave * 4) * 9);
        float acc[21];
#pragma unroll
        for (int o = 0; o < 21; ++o) {
            const float* wro = (o < 18 ? pw + (size_t)o * KTOT
                                       : aw + (size_t)(o - 18) * KTOT) + cb;
            float a = 0.f;
#pragma unroll
            for (int q = 0; q < 36; ++q) a += xv[q] * wro[q];
            acc[o] = a;
        }
        __syncthreads();                 // xs dead; alias reduce buffer over sm
        if (wave > 0) {
            float* red = &sm[((wave - 1) * 64 + lane) * 21];
#pragma unroll
            for (int o = 0; o < 21; ++o) red[o] = acc[o];
        }
        __syncthreads();
        if (wave == 0) {
#pragma unroll
            for (int r = 0; r < 7; ++r) {
                const float* red = &sm[(r * 64 + lane) * 21];
#pragma unroll
                for (int o = 0; o < 21; ++o) acc[o] += red[o];
            }
            int i = i0 + pi, j = j0 + pj;
            int ij = i * WW + j;
            float* op = offp + (size_t)((b * 4 + cq) * 18) * HWX + ij;
#pragma unroll
            for (int o = 0; o < 18; ++o) op[(size_t)o * HWX] = acc[o];
            float* ap = adp + (size_t)((b * 4 + cq) * 3) * HWX + ij;
#pragma unroll
            for (int o = 0; o < 3; ++o) ap[(size_t)o * HWX] = acc[18 + o];
        }
    } else if (bid < 1440) {
        // ================= wbf: conv_w fp32 -> bf16, fragment-linear ================
        int t = (bid - 1152) * 512 + tid;   // 288 blocks x 512 = 147456 exactly
        if (t < KTOT * OC) {
            int e    = t & 7;
            int lane = (t >> 3) & 63;
            int f    = (t >> 9) & 1;
            int rest = t >> 10;          // (wv*2+h)*18 + kt, 0..143
            int kt   = rest % 18;
            int wh   = rest / 18;
            int h    = wh & 1;
            int wv   = wh >> 1;
            int quad = lane >> 4, l15 = lane & 15;
            int o  = wv * 32 + f * 16 + l15;
            int r  = kt * 32 + quad * 8 + e;
            int n  = r >> 6;
            int cl = r & 63;
            int c  = h * 64 + cl;
            wbf[t] = (__bf16)cw[(size_t)o * KTOT + c * 9 + n];
        }
    } else {
        // ================= xT: x NCHW -> NHWC **bf16**, 48-col half-rows ============
        // NOTE: x is quantized to bf16 here (pre-interpolation). Halves gather bytes
        // and gather instruction count in deform. Interp still computed in f32.
        int blk = bid - 1440;            // 0..383: (b, i, jhalf)
        int b  = blk / (HH * 2);
        int rm = blk % (HH * 2);
        int i  = rm >> 1;
        int j0 = (rm & 1) * 48;
        float* tile = sm;                // [jl 48][c 129-pad]
        const float* src = x + (size_t)b * CC * HWX + (size_t)i * WW + j0;
        for (int idx = tid; idx < CC * 48; idx += 512) {
            int c = idx / 48, jl = idx - c * 48;
            tile[jl * 129 + c] = src[(size_t)c * HWX + jl];
        }
        __syncthreads();
        unsigned int* dst = (unsigned int*)(xT + ((size_t)b * HWX + (size_t)i * WW + j0) * CC);
        for (int idx = tid; idx < CC * 48 / 2; idx += 512) {
            int jl = idx >> 6, cp = idx & 63;    // pair index within row
            __bf16 b0 = (__bf16)tile[jl * 129 + cp * 2];
            __bf16 b1 = (__bf16)tile[jl * 129 + cp * 2 + 1];
            unsigned int u0 = (unsigned int)__builtin_bit_cast(unsigned short, b0);
            unsigned int u1 = (unsigned int)__builtin_bit_cast(unsigned short, b1);
            dst[idx] = u0 | (u1 << 16);
        }
    }
}

// ---------------- K1: sampling + MFMA GEMM, bf16 gather (half bytes, half instrs) -----
// grid = 1152 blocks, 256 thr, XCD-swizzled. Gather: thread = (px=tid>>4, gs=tid&15);
// gs spans the FULL 128 channels in 8-ch bf16x8 chunks -> 4 corners x 9 taps = 36
// 16B loads per thread (was 72), lanes 0..3 = one 64B line per quad. Interp in f32.
// LDS k' layout and 36-step MFMA accumulation order identical to round-9.
__global__ __launch_bounds__(256, 3) void deform_kernel(
    const __bf16* __restrict__ xT, const float* __restrict__ offp,
    const float* __restrict__ adp, const float* __restrict__ pb,
    const float* __restrict__ ab, const __bf16* __restrict__ wbf,
    float* __restrict__ out)
{
    __shared__ __align__(16) __bf16 xoff[PXB * ROWF];   // 37632 B, full K rows
    __shared__ int4   qidx[PXB * 9];                    // flat plane offsets (lt,rb,lb,rt)
    __shared__ float4 gwt[PXB * 9];                     // weights, zeroed when OOB

    int tid = threadIdx.x;
    // XCD-aware swizzle: contiguous slab per XCD (NWG % 8 == 0 -> bijective)
    int lb = (blockIdx.x & 7) * (NWG >> 3) + (blockIdx.x >> 3);
    int gid0 = lb * PXB;
    int b  = gid0 / HWX;
    int r0 = gid0 - b * HWX;
    int i  = r0 / WW;
    int j0 = r0 % WW;

    if (tid < PXB * 9) {
        int t = tid;
        int px = t / 9, n = t % 9;
        int j = j0 + px;
        int ij = i * WW + j;
        float offx = pb[n], offy = pb[9 + n], zad = ab[n % 3];
#pragma unroll
        for (int cq = 0; cq < 4; ++cq) {
            const float* op = offp + (size_t)((b * 4 + cq) * 18) * HWX + ij;
            offx += op[(size_t)n * HWX];
            offy += op[(size_t)(9 + n) * HWX];
            zad  += adp[(size_t)((b * 4 + cq) * 3 + (n % 3)) * HWX + ij];
        }
        float ad   = 2.f * (1.f - 1.f / (1.f + expf(-zad)));
        float pnx = (float)(n / 3 - 1), pny = (float)(n % 3 - 1);
        float pxf = (float)(i + 1) + pnx * (1.f + ad) + offx;
        float pyf = (float)(j + 1) + pny * (1.f + ad) + offy;
        float flx = floorf(pxf), fly = floorf(pyf);
        float qltx = fminf(fmaxf(flx, 0.f), 97.f);
        float qlty = fminf(fmaxf(fly, 0.f), 97.f);
        float qrbx = fminf(fmaxf(flx + 1.f, 0.f), 97.f);
        float qrby = fminf(fmaxf(fly + 1.f, 0.f), 97.f);
        bool mx = (pxf < 1.f) || (pxf > 96.f);
        bool my = (pyf < 1.f) || (pyf > 96.f);
        float pxm = mx ? flx : pxf; pxm = fminf(fmaxf(pxm, 0.f), 97.f);
        float pym = my ? fly : pyf; pym = fminf(fmaxf(pym, 0.f), 97.f);
        float glt = (1.f + (qltx - pxm)) * (1.f + (qlty - pym));
        float grb = (1.f - (qrbx - pxm)) * (1.f - (qrby - pym));
        float glb = (1.f + (qltx - pxm)) * (1.f - (qrby - pym));
        float grt = (1.f - (qrbx - pxm)) * (1.f + (qlty - pym));
        int ilt = (int)qltx, jlt = (int)qlty, irb = (int)qrbx, jrb = (int)qrby;
        bool m_lt = (ilt >= 1) & (ilt <= 96) & (jlt >= 1) & (jlt <= 96);
        bool m_rb = (irb >= 1) & (irb <= 96) & (jrb >= 1) & (jrb <= 96);
        bool m_lb = (ilt >= 1) & (ilt <= 96) & (jrb >= 1) & (jrb <= 96);
        bool m_rt = (irb >= 1) & (irb <= 96) & (jlt >= 1) & (jlt <= 96);
        // folded OOB: weight 0 + safe index 0 == (in-bounds ? x : 0) contribution
        qidx[t] = make_int4(m_lt ? (ilt - 1) * WW + (jlt - 1) : 0,
                            m_rb ? (irb - 1) * WW + (jrb - 1) : 0,
                            m_lb ? (ilt - 1) * WW + (jrb - 1) : 0,
                            m_rt ? (irb - 1) * WW + (jlt - 1) : 0);
        gwt[t]  = make_float4(m_lt ? glt : 0.f, m_rb ? grb : 0.f,
                              m_lb ? glb : 0.f, m_rt ? grt : 0.f);
    }
    __syncthreads();

    int wv = tid >> 6, lane = tid & 63;
    int quad = lane >> 4, l15 = lane & 15;
    int o0 = wv * 32 + l15;
    int o1 = o0 + 16;
    floatx4 acc0 = {0,0,0,0}, acc1 = {0,0,0,0};
    const __bf16* arow = &xoff[l15 * ROWF];
    const __bf16* wlan = wbf + (size_t)lane * 8;   // fragment-linear B base

    // ---- single-pass gather: 36 independent bf16x8 loads (full 128 ch per gs map) ----
    int gpx = tid >> 4;                 // gather pixel (quad-coalesced map)
    int gs  = tid & 15;                 // 8-channel group over full K
    int hsel = gs >> 3;                 // which K-half this group lands in
    int cl8  = (gs & 7) * 8;            // cl offset within half
    __bf16* gdst = &xoff[gpx * ROWF + hsel * KHALF + cl8];
    const int4*   qrow = &qidx[gpx * 9];
    const float4* grw  = &gwt[gpx * 9];
    const __bf16* xb = xT + (size_t)b * HWX * CC + gs * 8;

#pragma unroll
    for (int n = 0; n < 9; ++n) {
        int4 q = qrow[n];
        float4 g = grw[n];
        bf16x8 vlt = *(const bf16x8*)(xb + (size_t)q.x * CC);
        bf16x8 vrb = *(const bf16x8*)(xb + (size_t)q.y * CC);
        bf16x8 vlb = *(const bf16x8*)(xb + (size_t)q.z * CC);
        bf16x8 vrt = *(const bf16x8*)(xb + (size_t)q.w * CC);
        bf16x8 ov;   // interp in f32, same corner order: lt,rb,lb,rt
#pragma unroll
        for (int k = 0; k < 8; ++k)
            ov[k] = (__bf16)(g.x * (float)vlt[k] + g.y * (float)vrb[k]
                           + g.z * (float)vlb[k] + g.w * (float)vrt[k]);
        *(bf16x8*)(gdst + n * 64) = ov;   // k' = hsel*576 + tap*64 + cl, 16B store
    }
    __syncthreads();

    // ---- barrier-free 36-step MFMA chain (order identical to round-9) ----
#pragma unroll
    for (int h = 0; h < 2; ++h) {
        const __bf16* wb = wlan + (size_t)((wv * 2 + h) * 18) * 1024;
        const __bf16* ah = arow + h * KHALF;
#pragma unroll
        for (int kt = 0; kt < 18; ++kt) {
            bf16x8 a0 = *(const bf16x8*)(ah + kt * 32 + quad * 8);
            bf16x8 b0 = *(const bf16x8*)(wb + kt * 1024);
            bf16x8 b1 = *(const bf16x8*)(wb + kt * 1024 + 512);
            acc0 = __builtin_amdgcn_mfma_f32_16x16x32_bf16(a0, b0, acc0, 0, 0, 0);
            acc1 = __builtin_amdgcn_mfma_f32_16x16x32_bf16(a0, b1, acc1, 0, 0, 0);
        }
    }

#pragma unroll
    for (int rr = 0; rr < 4; ++rr) {
        int m0 = quad * 4 + rr;          // pixel 0..15
        int ja = j0 + m0;
        out[((b * OC + o0) * HH + i) * WW + ja] = acc0[rr];
        out[((b * OC + o1) * HH + i) * WW + ja] = acc1[rr];
    }
}

extern "C" void kernel_launch(void* const* d_in, const int* in_sizes, int n_in,
                              void* d_out, int out_size, void* d_ws, size_t ws_size,
                              hipStream_t stream)
{
    const float* x  = (const float*)d_in[0];
    const float* cw = (const float*)d_in[1];
    const float* pw = (const float*)d_in[2];
    const float* pb = (const float*)d_in[3];
    const float* aw = (const float*)d_in[4];
    const float* ab = (const float*)d_in[5];
    float* out = (float*)d_out;

    char* ws = (char*)d_ws;
    float*  offp = (float*)ws;                        // 2*4*18*9216 = 663552 fp32
    float*  adp  = offp + BB * 4 * 18 * HWX;          // 2*4*3*9216  = 221184 fp32
    __bf16* wbf  = (__bf16*)(adp + BB * 4 * 3 * HWX); // 147456 bf16 (16B-aligned)
    __bf16* xT   = wbf + (size_t)KTOT * OC;           // 2359296 bf16 (16B-aligned)
    // total ws use: ~8.6 MB

    pre_kernel<<<1824, 512, 0, stream>>>(pw, aw, cw, x, offp, adp, wbf, xT);
    deform_kernel<<<NWG, 256, 0, stream>>>(xT, offp, adp, pb, ab, wbf, out);
}

// Round 11
// 120.552 us; speedup vs baseline: 1.1328x; 1.0148x over previous
//
#include <hip/hip_runtime.h>
#include <hip/hip_bf16.h>
#include <math.h>

#define BB 2
#define CC 128
#define HH 96
#define WW 96
#define HWX (HH*WW)        // 9216
#define KTOT (CC*9)        // 1152
#define OC 128
#define KHALF 576          // deform K split: 64 channels per half
#define ROWF 1160          // 1152 + 8 pad; 2320 B row stride (16B-aligned, bank-stride 4)
#define QC 32              // offsets: channels per block
#define PXB 16             // pixels per deform block
#define NWG (BB*HWX/PXB)   // 1152 deform blocks

typedef __attribute__((ext_vector_type(8))) __bf16 bf16x8;
typedef __attribute__((ext_vector_type(4))) __bf16 bf16x4;
typedef __attribute__((ext_vector_type(4))) float floatx4;

// ---------------- K0: fused pre (offsets | wbf | xT-bf16) -----------------------------
// blocks [0,1152): offsets conv (weights s_loaded directly from pw/aw);
// blocks [1152,1440): conv_w fp32 -> bf16 fragment-linear; [1440,1824): x -> NHWC bf16.
__global__ __launch_bounds__(512) void pre_kernel(
    const float* __restrict__ pw, const float* __restrict__ aw,
    const float* __restrict__ cw, const float* __restrict__ x,
    float* __restrict__ offp, float* __restrict__ adp,
    __bf16* __restrict__ wbf, __bf16* __restrict__ xT)
{
    __shared__ float sm[9408];   // offsets: xs[32][10][10] in [0,3200), reduce [0,9408);
                                 // xT branch: tile[48][129] = 6192 floats
    int bid = blockIdx.x;
    int tid = threadIdx.x;

    if (bid < 1152) {
        // ================= offsets conv, c-quarter blocks, partial sums =============
        int cq = bid & 3;
        int rest = bid >> 2;
        int b = rest / 144;
        int t2 = rest % 144;
        int ti = t2 / 12, tj = t2 % 12;
        int i0 = ti * 8, j0 = tj * 8;
        float* xs = sm;

        for (int idx = tid; idx < 3200; idx += 512) {
            int cl = idx / 100; int r = idx % 100; int u = r / 10, v = r % 10;
            int gi = i0 + u - 1, gj = j0 + v - 1;
            float val = 0.f;
            if (gi >= 0 && gi < HH && gj >= 0 && gj < WW)
                val = x[((b * CC + cq * QC + cl) * HH + gi) * WW + gj];
            xs[idx] = val;
        }
        __syncthreads();

        int wave = tid >> 6, lane = tid & 63;
        int pi = lane >> 3, pj = lane & 7;

        // hoist the 36 x-values (4 ch x 9 taps) into VGPRs, fully unrolled
        float xv[36];
#pragma unroll
        for (int cc = 0; cc < 4; ++cc) {
            const float* xr = &xs[(wave * 4 + cc) * 100 + pi * 10 + pj];
#pragma unroll
            for (int tap = 0; tap < 9; ++tap)
                xv[cc * 9 + tap] = xr[(tap / 3) * 10 + (tap % 3)];
        }

        // weights: 36 contiguous floats per (o,wave) -> merged s_loads. Sum order
        // (cc,tap) ascending, identical to previous rounds -> bit-identical.
        int cb = __builtin_amdgcn_readfirstlane((cq * QC + wave * 4) * 9);
        float acc[21];
#pragma unroll
        for (int o = 0; o < 21; ++o) {
            const float* wro = (o < 18 ? pw + (size_t)o * KTOT
                                       : aw + (size_t)(o - 18) * KTOT) + cb;
            float a = 0.f;
#pragma unroll
            for (int q = 0; q < 36; ++q) a += xv[q] * wro[q];
            acc[o] = a;
        }
        __syncthreads();                 // xs dead; alias reduce buffer over sm
        if (wave > 0) {
            float* red = &sm[((wave - 1) * 64 + lane) * 21];
#pragma unroll
            for (int o = 0; o < 21; ++o) red[o] = acc[o];
        }
        __syncthreads();
        if (wave == 0) {
#pragma unroll
            for (int r = 0; r < 7; ++r) {
                const float* red = &sm[(r * 64 + lane) * 21];
#pragma unroll
                for (int o = 0; o < 21; ++o) acc[o] += red[o];
            }
            int i = i0 + pi, j = j0 + pj;
            int ij = i * WW + j;
            float* op = offp + (size_t)((b * 4 + cq) * 18) * HWX + ij;
#pragma unroll
            for (int o = 0; o < 18; ++o) op[(size_t)o * HWX] = acc[o];
            float* ap = adp + (size_t)((b * 4 + cq) * 3) * HWX + ij;
#pragma unroll
            for (int o = 0; o < 3; ++o) ap[(size_t)o * HWX] = acc[18 + o];
        }
    } else if (bid < 1440) {
        // ================= wbf: conv_w fp32 -> bf16, fragment-linear ================
        int t = (bid - 1152) * 512 + tid;   // 288 blocks x 512 = 147456 exactly
        if (t < KTOT * OC) {
            int e    = t & 7;
            int lane = (t >> 3) & 63;
            int f    = (t >> 9) & 1;
            int rest = t >> 10;          // (wv*2+h)*18 + kt, 0..143
            int kt   = rest % 18;
            int wh   = rest / 18;
            int h    = wh & 1;
            int wv   = wh >> 1;
            int quad = lane >> 4, l15 = lane & 15;
            int o  = wv * 32 + f * 16 + l15;
            int r  = kt * 32 + quad * 8 + e;
            int n  = r >> 6;
            int cl = r & 63;
            int c  = h * 64 + cl;
            wbf[t] = (__bf16)cw[(size_t)o * KTOT + c * 9 + n];
        }
    } else {
        // ================= xT: x NCHW -> NHWC **bf16**, 48-col half-rows ============
        int blk = bid - 1440;            // 0..383: (b, i, jhalf)
        int b  = blk / (HH * 2);
        int rm = blk % (HH * 2);
        int i  = rm >> 1;
        int j0 = (rm & 1) * 48;
        float* tile = sm;                // [jl 48][c 129-pad]
        const float* src = x + (size_t)b * CC * HWX + (size_t)i * WW + j0;
        for (int idx = tid; idx < CC * 48; idx += 512) {
            int c = idx / 48, jl = idx - c * 48;
            tile[jl * 129 + c] = src[(size_t)c * HWX + jl];
        }
        __syncthreads();
        unsigned int* dst = (unsigned int*)(xT + ((size_t)b * HWX + (size_t)i * WW + j0) * CC);
        for (int idx = tid; idx < CC * 48 / 2; idx += 512) {
            int jl = idx >> 6, cp = idx & 63;    // pair index within row
            __bf16 b0 = (__bf16)tile[jl * 129 + cp * 2];
            __bf16 b1 = (__bf16)tile[jl * 129 + cp * 2 + 1];
            unsigned int u0 = (unsigned int)__builtin_bit_cast(unsigned short, b0);
            unsigned int u1 = (unsigned int)__builtin_bit_cast(unsigned short, b1);
            dst[idx] = u0 | (u1 << 16);
        }
    }
}

// ---------------- K1: sampling + MFMA GEMM, bf16 gather, 4 blocks/CU ------------------
// grid = 1152 blocks, 256 thr, XCD-swizzled. LDS trimmed to 40,576 B (ROWF 1176->1160,
// qidx int4->short4) -> 4 resident blocks/CU (was 3): +33% TLP to hide gather/B-stream
// latency. Gather map, interp expression, k' layout, and 36-step MFMA accumulation
// order identical to round-10 -> bit-identical output.
__global__ __launch_bounds__(256, 4) void deform_kernel(
    const __bf16* __restrict__ xT, const float* __restrict__ offp,
    const float* __restrict__ adp, const float* __restrict__ pb,
    const float* __restrict__ ab, const __bf16* __restrict__ wbf,
    float* __restrict__ out)
{
    __shared__ __align__(16) __bf16 xoff[PXB * ROWF];   // 37120 B, full K rows
    __shared__ short4 qidx[PXB * 9];                    // flat plane offsets (lt,rb,lb,rt)
    __shared__ float4 gwt[PXB * 9];                     // weights, zeroed when OOB

    int tid = threadIdx.x;
    // XCD-aware swizzle: contiguous slab per XCD (NWG % 8 == 0 -> bijective)
    int lb = (blockIdx.x & 7) * (NWG >> 3) + (blockIdx.x >> 3);
    int gid0 = lb * PXB;
    int b  = gid0 / HWX;
    int r0 = gid0 - b * HWX;
    int i  = r0 / WW;
    int j0 = r0 % WW;

    if (tid < PXB * 9) {
        int t = tid;
        int px = t / 9, n = t % 9;
        int j = j0 + px;
        int ij = i * WW + j;
        float offx = pb[n], offy = pb[9 + n], zad = ab[n % 3];
#pragma unroll
        for (int cq = 0; cq < 4; ++cq) {
            const float* op = offp + (size_t)((b * 4 + cq) * 18) * HWX + ij;
            offx += op[(size_t)n * HWX];
            offy += op[(size_t)(9 + n) * HWX];
            zad  += adp[(size_t)((b * 4 + cq) * 3 + (n % 3)) * HWX + ij];
        }
        float ad   = 2.f * (1.f - 1.f / (1.f + expf(-zad)));
        float pnx = (float)(n / 3 - 1), pny = (float)(n % 3 - 1);
        float pxf = (float)(i + 1) + pnx * (1.f + ad) + offx;
        float pyf = (float)(j + 1) + pny * (1.f + ad) + offy;
        float flx = floorf(pxf), fly = floorf(pyf);
        float qltx = fminf(fmaxf(flx, 0.f), 97.f);
        float qlty = fminf(fmaxf(fly, 0.f), 97.f);
        float qrbx = fminf(fmaxf(flx + 1.f, 0.f), 97.f);
        float qrby = fminf(fmaxf(fly + 1.f, 0.f), 97.f);
        bool mx = (pxf < 1.f) || (pxf > 96.f);
        bool my = (pyf < 1.f) || (pyf > 96.f);
        float pxm = mx ? flx : pxf; pxm = fminf(fmaxf(pxm, 0.f), 97.f);
        float pym = my ? fly : pyf; pym = fminf(fmaxf(pym, 0.f), 97.f);
        float glt = (1.f + (qltx - pxm)) * (1.f + (qlty - pym));
        float grb = (1.f - (qrbx - pxm)) * (1.f - (qrby - pym));
        float glb = (1.f + (qltx - pxm)) * (1.f - (qrby - pym));
        float grt = (1.f - (qrbx - pxm)) * (1.f + (qlty - pym));
        int ilt = (int)qltx, jlt = (int)qlty, irb = (int)qrbx, jrb = (int)qrby;
        bool m_lt = (ilt >= 1) & (ilt <= 96) & (jlt >= 1) & (jlt <= 96);
        bool m_rb = (irb >= 1) & (irb <= 96) & (jrb >= 1) & (jrb <= 96);
        bool m_lb = (ilt >= 1) & (ilt <= 96) & (jrb >= 1) & (jrb <= 96);
        bool m_rt = (irb >= 1) & (irb <= 96) & (jlt >= 1) & (jlt <= 96);
        // folded OOB: weight 0 + safe index 0 == (in-bounds ? x : 0) contribution
        qidx[t] = make_short4((short)(m_lt ? (ilt - 1) * WW + (jlt - 1) : 0),
                              (short)(m_rb ? (irb - 1) * WW + (jrb - 1) : 0),
                              (short)(m_lb ? (ilt - 1) * WW + (jrb - 1) : 0),
                              (short)(m_rt ? (irb - 1) * WW + (jlt - 1) : 0));
        gwt[t]  = make_float4(m_lt ? glt : 0.f, m_rb ? grb : 0.f,
                              m_lb ? glb : 0.f, m_rt ? grt : 0.f);
    }
    __syncthreads();

    int wv = tid >> 6, lane = tid & 63;
    int quad = lane >> 4, l15 = lane & 15;
    int o0 = wv * 32 + l15;
    int o1 = o0 + 16;
    floatx4 acc0 = {0,0,0,0}, acc1 = {0,0,0,0};
    const __bf16* arow = &xoff[l15 * ROWF];
    const __bf16* wlan = wbf + (size_t)lane * 8;   // fragment-linear B base

    // ---- single-pass gather: 36 independent bf16x8 loads (full 128 ch per gs map) ----
    int gpx = tid >> 4;                 // gather pixel (quad-coalesced map)
    int gs  = tid & 15;                 // 8-channel group over full K
    int hsel = gs >> 3;                 // which K-half this group lands in
    int cl8  = (gs & 7) * 8;            // cl offset within half
    __bf16* gdst = &xoff[gpx * ROWF + hsel * KHALF + cl8];
    const short4* qrow = &qidx[gpx * 9];
    const float4* grw  = &gwt[gpx * 9];
    const __bf16* xb = xT + (size_t)b * HWX * CC + gs * 8;

#pragma unroll
    for (int n = 0; n < 9; ++n) {
        short4 qs = qrow[n];
        float4 g = grw[n];
        bf16x8 vlt = *(const bf16x8*)(xb + (size_t)(int)qs.x * CC);
        bf16x8 vrb = *(const bf16x8*)(xb + (size_t)(int)qs.y * CC);
        bf16x8 vlb = *(const bf16x8*)(xb + (size_t)(int)qs.z * CC);
        bf16x8 vrt = *(const bf16x8*)(xb + (size_t)(int)qs.w * CC);
        bf16x8 ov;   // interp in f32, same corner order: lt,rb,lb,rt
#pragma unroll
        for (int k = 0; k < 8; ++k)
            ov[k] = (__bf16)(g.x * (float)vlt[k] + g.y * (float)vrb[k]
                           + g.z * (float)vlb[k] + g.w * (float)vrt[k]);
        *(bf16x8*)(gdst + n * 64) = ov;   // k' = hsel*576 + tap*64 + cl, 16B store
    }
    __syncthreads();

    // ---- barrier-free 36-step MFMA chain (order identical to round-10) ----
#pragma unroll
    for (int h = 0; h < 2; ++h) {
        const __bf16* wb = wlan + (size_t)((wv * 2 + h) * 18) * 1024;
        const __bf16* ah = arow + h * KHALF;
#pragma unroll
        for (int kt = 0; kt < 18; ++kt) {
            bf16x8 a0 = *(const bf16x8*)(ah + kt * 32 + quad * 8);
            bf16x8 b0 = *(const bf16x8*)(wb + kt * 1024);
            bf16x8 b1 = *(const bf16x8*)(wb + kt * 1024 + 512);
            acc0 = __builtin_amdgcn_mfma_f32_16x16x32_bf16(a0, b0, acc0, 0, 0, 0);
            acc1 = __builtin_amdgcn_mfma_f32_16x16x32_bf16(a0, b1, acc1, 0, 0, 0);
        }
    }

#pragma unroll
    for (int rr = 0; rr < 4; ++rr) {
        int m0 = quad * 4 + rr;          // pixel 0..15
        int ja = j0 + m0;
        out[((b * OC + o0) * HH + i) * WW + ja] = acc0[rr];
        out[((b * OC + o1) * HH + i) * WW + ja] = acc1[rr];
    }
}

extern "C" void kernel_launch(void* const* d_in, const int* in_sizes, int n_in,
                              void* d_out, int out_size, void* d_ws, size_t ws_size,
                              hipStream_t stream)
{
    const float* x  = (const float*)d_in[0];
    const float* cw = (const float*)d_in[1];
    const float* pw = (const float*)d_in[2];
    const float* pb = (const float*)d_in[3];
    const float* aw = (const float*)d_in[4];
    const float* ab = (const float*)d_in[5];
    float* out = (float*)d_out;

    char* ws = (char*)d_ws;
    float*  offp = (float*)ws;                        // 2*4*18*9216 = 663552 fp32
    float*  adp  = offp + BB * 4 * 18 * HWX;          // 2*4*3*9216  = 221184 fp32
    __bf16* wbf  = (__bf16*)(adp + BB * 4 * 3 * HWX); // 147456 bf16 (16B-aligned)
    __bf16* xT   = wbf + (size_t)KTOT * OC;           // 2359296 bf16 (16B-aligned)
    // total ws use: ~8.6 MB

    pre_kernel<<<1824, 512, 0, stream>>>(pw, aw, cw, x, offp, adp, wbf, xT);
    deform_kernel<<<NWG, 256, 0, stream>>>(xT, offp, adp, pb, ab, wbf, out);
}